// Round 6
// baseline (106.640 us; speedup 1.0000x reference)
//
#include <hip/hip_runtime.h>
#include <math.h>

// AR-GAS Student-t filter, K = 4194304 sequential steps.
// Chunked scan with burn-in (contractive map, redundancy 13x).
// R6: ILP-2 — two independent chains per thread (interleaved steps), halving
// total wave-steps at equal redundancy and filling chain-latency bubbles.
// State tracked as u = nu*s2 (10 VALU/step instead of 12). Predicated
// exact-seed path for block 0 (no divergent slow loop). 512 blocks x 256
// thr = 2 waves/SIMD, 42 KB LDS (2 blocks/CU). Swizzle +4-per-16 keeps
// b128 alignment, uniform +20 stride/group, 2-way banks (free).

#define CHUNK  16
#define BURN   192
#define NG     (BURN / CHUNK)            // 12 burn groups
#define BLOCK  256
#define HALF   (BLOCK * CHUNK)           // 4096
#define OUTW   (2 * HALF)                // 8192 outputs per block
#define REGION (OUTW + BURN)             // 8384 staged y elements
#define SWZ(e) ((e) + 4 * ((e) >> 4))    // +4 floats per 16; keeps 4-align
#define SY_PAD 10480                     // > SWZ(REGION-1) = 10475

__global__ __launch_bounds__(BLOCK, 2)
void ar_gas_kernel(const float* __restrict__ y,
                   const float* __restrict__ p_last_mu,
                   const float* __restrict__ p_last_s2,
                   const float* __restrict__ p_amu,
                   const float* __restrict__ p_as,
                   const float* __restrict__ p_bmu,
                   const float* __restrict__ p_bs,
                   const float* __restrict__ p_wmu,
                   const float* __restrict__ p_ws,
                   const float* __restrict__ p_nu,
                   const float* __restrict__ p_str,
                   float* __restrict__ out,
                   int n)
{
    __shared__ __align__(16) float sy[SY_PAD];
    const int t     = threadIdx.x;
    const int blk   = blockIdx.x;
    const int gbase = blk * OUTW - BURN;     // global index of LDS elem 0

    const float nu       = *p_nu;
    const float strength = *p_str;
    const float a_mu = (*p_amu) * strength;
    const float a_s  = (*p_as)  * strength;
    const float b_mu = *p_bmu;
    const float b_s  = *p_bs;
    const float w_mu = *p_wmu;
    const float w_s  = *p_ws;

    // u = nu*s2 state transform:
    //   r = y-mu; den = u + r^2; t2 = u*r/den          (= nu*s2*r/den)
    //   mu' = w_mu + b_mu*mu + (b_mu*a_mu*k1)*t2       k1 = (nu+1)/nu
    //   u'  = nu*w_s + b_s*(1-a_s)*u + (nu*b_s*a_s*k1)*(t2*r)
    const float inv_nu = __builtin_amdgcn_rcpf(nu);
    const float k1   = (nu + 1.0f) * inv_nu;
    const float bamk = b_mu * a_mu * k1;
    const float bask = nu * b_s * a_s * k1;
    const float c3   = b_s * (1.0f - a_s);
    const float wsn  = nu * w_s;

    // ---- stage y region: coalesced float4 global loads -> swizzled LDS ----
    #pragma unroll
    for (int it = 0; it < 9; ++it) {
        int idx = (t + BLOCK * it) * 4;      // idx%16 in {0,4,8,12}
        if (idx < REGION) {
            int g = gbase + idx;
            float4 v = make_float4(0.f, 0.f, 0.f, 0.f);
            if (g >= 0) v = *(const float4*)(y + g);   // block-0 pre-pad = 0
            *(float4*)(sy + SWZ(idx)) = v;             // 16B-aligned
        }
    }
    __syncthreads();

    // ---- initial states ----
    // chain A: emits global [blk*OUTW + 16t, +16);  burn elems 16(t+g)
    // chain B: emits [... + HALF + 16t, +16);       burn elems HALF+16(t+g)
    const int  skipA = (blk == 0 && t <= NG) ? (NG - t) : 0;
    const float mu_st = w_mu * __builtin_amdgcn_rcpf(fmaxf(1.0f - b_mu, 1e-12f));
    const float u_st  = wsn  * __builtin_amdgcn_rcpf(fmaxf(1.0f - b_s,  1e-12f));
    float muA, uA;
    if (skipA > 0 || (blk == 0 && t == NG)) {   // exact seed at global index 0
        muA = *p_last_mu;
        uA  = nu * (*p_last_s2);     // "last_sigma" is the variance
    } else {
        muA = mu_st; uA = u_st;      // stationary guess; burn erases it
    }
    float muB = mu_st, uB = u_st;

#define STEPA(yv) do {                                   \
        float r   = (yv) - muA;                          \
        float den = fmaf(r, r, uA);                      \
        float inv = __builtin_amdgcn_rcpf(den);          \
        float t2  = (uA * r) * inv;                      \
        muA = fmaf(bamk, t2, fmaf(b_mu, muA, w_mu));     \
        uA  = fmaf(bask, t2 * r, fmaf(c3, uA, wsn));     \
    } while (0)
#define STEPB(yv) do {                                   \
        float r   = (yv) - muB;                          \
        float den = fmaf(r, r, uB);                      \
        float inv = __builtin_amdgcn_rcpf(den);          \
        float t2  = (uB * r) * inv;                      \
        muB = fmaf(bamk, t2, fmaf(b_mu, muB, w_mu));     \
        uB  = fmaf(bask, t2 * r, fmaf(c3, uB, wsn));     \
    } while (0)
#define STEP2(va, vb) do { STEPA(va); STEPB(vb); } while (0)
#define LD(fi) (*(const float4*)(sy + (fi)))

    // ---- burn-in: 12 groups x (16 A-steps + 16 B-steps interleaved) ----
    int qA = 20 * t;                 // SWZ(16t);        +20 per group
    int qB = 5120 + 20 * t;          // SWZ(HALF + 16t)
    #pragma unroll 1
    for (int g = 0; g < NG; ++g) {
        float4 a0 = LD(qA), a1 = LD(qA + 4), a2 = LD(qA + 8), a3 = LD(qA + 12);
        float4 b0 = LD(qB), b1 = LD(qB + 4), b2 = LD(qB + 8), b3 = LD(qB + 12);
        float muA0 = muA, uA0 = uA;          // for predicated restore
        STEP2(a0.x, b0.x); STEP2(a0.y, b0.y); STEP2(a0.z, b0.z); STEP2(a0.w, b0.w);
        STEP2(a1.x, b1.x); STEP2(a1.y, b1.y); STEP2(a1.z, b1.z); STEP2(a1.w, b1.w);
        STEP2(a2.x, b2.x); STEP2(a2.y, b2.y); STEP2(a2.z, b2.z); STEP2(a2.w, b2.w);
        STEP2(a3.x, b3.x); STEP2(a3.y, b3.y); STEP2(a3.z, b3.z); STEP2(a3.w, b3.w);
        if (g < skipA) { muA = muA0; uA = uA0; }  // block-0 exact lanes: hold
        qA += 20; qB += 20;
    }
    // qA = SWZ(16t+192), qB = SWZ(HALF+16t+192): this thread's emit slots.

    // all cross-thread burn reads must complete before in-place mu writes:
    __syncthreads();

    // ---- emit: 16+16 steps; mu in-place over consumed y; sigma -> regs ----
    float sgA[16], sgB[16];
    {
        float4 a0 = LD(qA), a1 = LD(qA + 4), a2 = LD(qA + 8), a3 = LD(qA + 12);
        float4 b0 = LD(qB), b1 = LD(qB + 4), b2 = LD(qB + 8), b3 = LD(qB + 12);
        float4 mA, mB;
#define SQA(j) sgA[j] = __builtin_amdgcn_sqrtf(uA * inv_nu)
#define SQB(j) sgB[j] = __builtin_amdgcn_sqrtf(uB * inv_nu)
#define EQ(va, vb, j, c) do {                       \
            STEPA(va); mA.c = muA; SQA(j);          \
            STEPB(vb); mB.c = muB; SQB(j);          \
        } while (0)
        EQ(a0.x, b0.x,  0, x); EQ(a0.y, b0.y,  1, y);
        EQ(a0.z, b0.z,  2, z); EQ(a0.w, b0.w,  3, w);
        *(float4*)(sy + qA) = mA; *(float4*)(sy + qB) = mB;
        EQ(a1.x, b1.x,  4, x); EQ(a1.y, b1.y,  5, y);
        EQ(a1.z, b1.z,  6, z); EQ(a1.w, b1.w,  7, w);
        *(float4*)(sy + qA + 4) = mA; *(float4*)(sy + qB + 4) = mB;
        EQ(a2.x, b2.x,  8, x); EQ(a2.y, b2.y,  9, y);
        EQ(a2.z, b2.z, 10, z); EQ(a2.w, b2.w, 11, w);
        *(float4*)(sy + qA + 8) = mA; *(float4*)(sy + qB + 8) = mB;
        EQ(a3.x, b3.x, 12, x); EQ(a3.y, b3.y, 13, y);
        EQ(a3.z, b3.z, 14, z); EQ(a3.w, b3.w, 15, w);
        *(float4*)(sy + qA + 12) = mA; *(float4*)(sy + qB + 12) = mB;
#undef EQ
#undef SQA
#undef SQB
    }
#undef LD
#undef STEP2
#undef STEPB
#undef STEPA
    __syncthreads();

    // ---- coalesced copy-out: mu ----
    const int obase = blk * OUTW;
    #pragma unroll
    for (int it = 0; it < 8; ++it) {
        int idx = (t + BLOCK * it) * 4;
        int f   = SWZ(BURN + idx);           // 4 contiguous padded slots
        *(float4*)(out + obase + idx) =
            make_float4(sy[f], sy[f + 1], sy[f + 2], sy[f + 3]);
    }
    __syncthreads();

    // ---- sigma -> same LDS slots, then coalesced copy-out ----
    *(float4*)(sy + qA)      = make_float4(sgA[ 0], sgA[ 1], sgA[ 2], sgA[ 3]);
    *(float4*)(sy + qA +  4) = make_float4(sgA[ 4], sgA[ 5], sgA[ 6], sgA[ 7]);
    *(float4*)(sy + qA +  8) = make_float4(sgA[ 8], sgA[ 9], sgA[10], sgA[11]);
    *(float4*)(sy + qA + 12) = make_float4(sgA[12], sgA[13], sgA[14], sgA[15]);
    *(float4*)(sy + qB)      = make_float4(sgB[ 0], sgB[ 1], sgB[ 2], sgB[ 3]);
    *(float4*)(sy + qB +  4) = make_float4(sgB[ 4], sgB[ 5], sgB[ 6], sgB[ 7]);
    *(float4*)(sy + qB +  8) = make_float4(sgB[ 8], sgB[ 9], sgB[10], sgB[11]);
    *(float4*)(sy + qB + 12) = make_float4(sgB[12], sgB[13], sgB[14], sgB[15]);
    __syncthreads();
    #pragma unroll
    for (int it = 0; it < 8; ++it) {
        int idx = (t + BLOCK * it) * 4;
        int f   = SWZ(BURN + idx);
        *(float4*)(out + n + obase + idx) =
            make_float4(sy[f], sy[f + 1], sy[f + 2], sy[f + 3]);
    }
}

extern "C" void kernel_launch(void* const* d_in, const int* in_sizes, int n_in,
                              void* d_out, int out_size, void* d_ws, size_t ws_size,
                              hipStream_t stream) {
    const float* y = (const float*)d_in[0];
    const int n    = in_sizes[0];              // 4194304 = 512 * 8192
    const int grid = n / OUTW;                 // 512 blocks

    ar_gas_kernel<<<grid, BLOCK, 0, stream>>>(
        y,
        (const float*)d_in[1],  // last_mu
        (const float*)d_in[2],  // last_sigma (variance)
        (const float*)d_in[3],  // alpha_mu
        (const float*)d_in[4],  // alpha_sigma
        (const float*)d_in[5],  // beta_mu
        (const float*)d_in[6],  // beta_sigma
        (const float*)d_in[7],  // omega_mu
        (const float*)d_in[8],  // omega_sigma
        (const float*)d_in[9],  // nu
        (const float*)d_in[10], // norm_strength
        (float*)d_out, n);
}